// Round 2
// baseline (7403.298 us; speedup 1.0000x reference)
//
#include <hip/hip_runtime.h>
#include <math.h>

#define HH 96
#define WW 96
#define HW 9216
#define TT 5

__device__ __forceinline__ float sigf(float x) { return 1.0f / (1.0f + expf(-x)); }

// ---------------------------------------------------------------------------
// Generic 3x3 conv, pad=1, over 96x96 images. Input = concat(srcA[ICA], srcB[ICB]).
// Block: 256 threads; tile = 8 rows x 32 cols, 16 output channels.
// Each thread: 2 oc x 8 px.
// ---------------------------------------------------------------------------
template<int ICA, int ICB, bool PERM_OUT>
__global__ __launch_bounds__(256) void conv3x3_kernel(
    const float* __restrict__ srcA, long strideA,
    const float* __restrict__ srcB, long strideB,
    const float* __restrict__ wgt,  const float* __restrict__ bias,
    float* __restrict__ out, long strideOut, int OC)
{
    constexpr int IC = ICA + ICB;
    __shared__ float sIn[8][10][36];   // [ic][row(-1..8)][col(-1..32)] halo-shifted
    __shared__ float sW[8][16][9];     // [ic][oc][k]

    const int tid = threadIdx.x;
    const int tY = blockIdx.x / 3;          // 12 row tiles
    const int tX = blockIdx.x % 3;          // 3 col tiles
    const int ocBase = blockIdx.y * 16;
    const int img = blockIdx.z;

    long outImg;
    if (PERM_OUT) {
        int t = img >> 1, b = img & 1;       // img = t*2 + b  ->  out at (b*T + t)
        outImg = (long)(b * TT + t) * strideOut;
    } else {
        outImg = (long)img * strideOut;
    }

    const int ocp = tid & 7;        // oc-pair id
    const int pg  = tid >> 3;       // pixel group 0..31
    const int lr  = pg >> 2;        // local row 0..7
    const int cb  = (pg & 3) * 8;   // col base 0,8,16,24

    float acc0[8], acc1[8];
#pragma unroll
    for (int j = 0; j < 8; ++j) { acc0[j] = 0.f; acc1[j] = 0.f; }

    const float* baseA = srcA + (long)img * strideA;

    for (int ic0 = 0; ic0 < IC; ic0 += 8) {
        // ---- stage input tile: 8 ic x 10 rows x 34 cols
        for (int i = tid; i < 8 * 10 * 34; i += 256) {
            int icl = i / 340;
            int rem = i - icl * 340;
            int r = rem / 34;
            int cx = rem - r * 34;
            int gy = tY * 8 + r - 1;
            int gx = tX * 32 + cx - 1;
            float v = 0.f;
            if (gy >= 0 && gy < HH && gx >= 0 && gx < WW) {
                int icg = ic0 + icl;
                if (ICB == 0) {
                    v = baseA[(long)icg * HW + gy * WW + gx];
                } else {
                    if (icg < ICA) {
                        v = baseA[(long)icg * HW + gy * WW + gx];
                    } else {
                        v = srcB[(long)img * strideB + (long)(icg - ICA) * HW + gy * WW + gx];
                    }
                }
            }
            sIn[icl][r][cx] = v;
        }
        // ---- stage weights: 8 ic x 16 oc x 9
        for (int i = tid; i < 8 * 16 * 9; i += 256) {
            int icl = i / 144;
            int rem = i - icl * 144;
            int ocl = rem / 9;
            int kk = rem - ocl * 9;
            int ocg = ocBase + ocl;
            float v = 0.f;
            if (ocg < OC) v = wgt[((long)ocg * IC + (ic0 + icl)) * 9 + kk];
            sW[icl][ocl][kk] = v;
        }
        __syncthreads();

#pragma unroll
        for (int icl = 0; icl < 8; ++icl) {
            float w0a[9], w1a[9];
#pragma unroll
            for (int q = 0; q < 9; ++q) {
                w0a[q] = sW[icl][ocp * 2][q];
                w1a[q] = sW[icl][ocp * 2 + 1][q];
            }
#pragma unroll
            for (int ky = 0; ky < 3; ++ky) {
                float in[10];
#pragma unroll
                for (int q = 0; q < 10; ++q) in[q] = sIn[icl][lr + ky][cb + q];
#pragma unroll
                for (int kx = 0; kx < 3; ++kx) {
                    float w0 = w0a[ky * 3 + kx];
                    float w1 = w1a[ky * 3 + kx];
#pragma unroll
                    for (int j = 0; j < 8; ++j) {
                        acc0[j] = fmaf(in[j + kx], w0, acc0[j]);
                        acc1[j] = fmaf(in[j + kx], w1, acc1[j]);
                    }
                }
            }
        }
        __syncthreads();
    }

    // ---- epilogue
    const int gy = tY * 8 + lr;
    const int gxb = tX * 32 + cb;
    const int oc0 = ocBase + ocp * 2;
    if (oc0 < OC) {
        float b0 = bias[oc0];
        float* op = out + outImg + (long)oc0 * HW + gy * WW + gxb;
#pragma unroll
        for (int j = 0; j < 8; ++j) op[j] = acc0[j] + b0;
    }
    if (oc0 + 1 < OC) {
        float b1 = bias[oc0 + 1];
        float* op = out + outImg + (long)(oc0 + 1) * HW + gy * WW + gxb;
#pragma unroll
        for (int j = 0; j < 8; ++j) op[j] = acc1[j] + b1;
    }
}

// ---------------------------------------------------------------------------
// Deformable sampling: one thread per (b, g, k, pixel).
// Writes samp[b][c*9+k][p] for c = g*8..g*8+7 (matches dcn_w (128,64,9) layout).
// ---------------------------------------------------------------------------
__global__ __launch_bounds__(256) void dcn_sample_kernel(
    const float* __restrict__ h,    // [B][64][HW]
    const float* __restrict__ om,   // [B][216][HW]
    float* __restrict__ samp)       // [B][576][HW]
{
    int i = blockIdx.x * 256 + threadIdx.x;   // B*G*KK*HW
    int p = i % HW;
    int r = i / HW;
    int k = r % 9;
    int g = (r / 9) % 8;
    int b = r / 72;
    int y = p / WW, x = p - (p / WW) * WW;
    int ky = k / 3, kx = k - ky * 3;

    const float* omb = om + (long)b * 216 * HW;
    float offy = omb[(g * 18 + k * 2) * HW + p];
    float offx = omb[(g * 18 + k * 2 + 1) * HW + p];
    float m = sigf(omb[(144 + g * 9 + k) * HW + p]);

    float py = (float)(y + ky - 1) + offy;
    float px = (float)(x + kx - 1) + offx;
    float y0f = floorf(py), x0f = floorf(px);
    float wy = py - y0f, wx = px - x0f;
    int y0 = (int)y0f, x0 = (int)x0f;
    int y1 = y0 + 1, x1 = x0 + 1;

    bool vy0 = (y0 >= 0) && (y0 < HH), vy1 = (y1 >= 0) && (y1 < HH);
    bool vx0 = (x0 >= 0) && (x0 < WW), vx1 = (x1 >= 0) && (x1 < WW);
    int cy0 = min(max(y0, 0), HH - 1), cy1 = min(max(y1, 0), HH - 1);
    int cx0 = min(max(x0, 0), WW - 1), cx1 = min(max(x1, 0), WW - 1);
    int i00 = cy0 * WW + cx0, i01 = cy0 * WW + cx1;
    int i10 = cy1 * WW + cx0, i11 = cy1 * WW + cx1;
    float w00 = (1.f - wy) * (1.f - wx) * ((vy0 && vx0) ? m : 0.f);
    float w01 = (1.f - wy) * wx         * ((vy0 && vx1) ? m : 0.f);
    float w10 = wy * (1.f - wx)         * ((vy1 && vx0) ? m : 0.f);
    float w11 = wy * wx                 * ((vy1 && vx1) ? m : 0.f);

    const float* hb = h + ((long)b * 64 + g * 8) * HW;
    float* sb = samp + ((long)b * 576 + (long)(g * 8) * 9 + k) * HW + p;
#pragma unroll
    for (int cg = 0; cg < 8; ++cg) {
        const float* hp = hb + (long)cg * HW;
        float v = w00 * hp[i00] + w01 * hp[i01] + w10 * hp[i10] + w11 * hp[i11];
        sb[(long)(cg * 9) * HW] = v;
    }
}

// ---------------------------------------------------------------------------
// 1x1 "conv" (the DCN einsum): out[b][o][p] = relu(bias[o] + sum_ck w[o][ck]*samp[b][ck][p])
// K = 576, OC = 128. Block: 256 px x 32 oc; thread: 4 oc x 8 px.
// ---------------------------------------------------------------------------
__global__ __launch_bounds__(256) void conv1x1_relu_kernel(
    const float* __restrict__ src,   // [B][576][HW]
    const float* __restrict__ wgt,   // [128][576]
    const float* __restrict__ bias,  // [128]
    float* __restrict__ out)         // [B][128][HW]
{
    __shared__ float sX[8][256];
    __shared__ float sWk[8][32];
    const int tid = threadIdx.x;
    const int pt = blockIdx.x;            // 36 pixel tiles
    const int ocBase = blockIdx.y * 32;   // 4 oc tiles
    const int b = blockIdx.z;

    const int ocq = tid & 7;
    const int pg = tid >> 3;
    const int oc_l = ocq * 4;
    const int px = pg * 8;

    float acc[4][8];
#pragma unroll
    for (int o = 0; o < 4; ++o)
#pragma unroll
        for (int j = 0; j < 8; ++j) acc[o][j] = 0.f;

    const float* sbase = src + (long)b * 576 * HW + pt * 256;

    for (int c0 = 0; c0 < 576; c0 += 8) {
        for (int i = tid; i < 2048; i += 256) {
            int icl = i >> 8; int p = i & 255;
            sX[icl][p] = sbase[(long)(c0 + icl) * HW + p];
        }
        {
            int icl = tid >> 5; int ocl = tid & 31;
            sWk[icl][ocl] = wgt[(long)(ocBase + ocl) * 576 + c0 + icl];
        }
        __syncthreads();
#pragma unroll
        for (int icl = 0; icl < 8; ++icl) {
            float wa[4], xv[8];
#pragma unroll
            for (int o = 0; o < 4; ++o) wa[o] = sWk[icl][oc_l + o];
#pragma unroll
            for (int j = 0; j < 8; ++j) xv[j] = sX[icl][px + j];
#pragma unroll
            for (int o = 0; o < 4; ++o)
#pragma unroll
                for (int j = 0; j < 8; ++j)
                    acc[o][j] = fmaf(wa[o], xv[j], acc[o][j]);
        }
        __syncthreads();
    }

#pragma unroll
    for (int o = 0; o < 4; ++o) {
        int oc = ocBase + oc_l + o;
        float bv = bias[oc];
        float* op = out + (long)b * 128 * HW + (long)oc * HW + pt * 256 + px;
#pragma unroll
        for (int j = 0; j < 8; ++j) op[j] = fmaxf(acc[o][j] + bv, 0.f);
    }
}

// ---------------------------------------------------------------------------
// LSTM gates: c2 = sig(cf)*c + sig(ci)*tanh(cg); h2 = sig(co)*tanh(c2)
// ---------------------------------------------------------------------------
__global__ __launch_bounds__(256) void gates_kernel(
    const float* __restrict__ cc,   // [B][256][HW]  (ci|cf|co|cg each 64ch)
    float* __restrict__ h, float* __restrict__ c,
    float* __restrict__ hseq)       // dst for this (dir, t): [B][64][HW]
{
    int i = blockIdx.x * 256 + threadIdx.x;   // B*64*HW
    int p = i % (64 * HW);
    int b = i / (64 * HW);
    const float* ccb = cc + (long)b * 256 * HW;
    float ci = ccb[p];
    float cf = ccb[64 * HW + p];
    float co = ccb[128 * HW + p];
    float cg = ccb[192 * HW + p];
    float cold = c[i];
    float c2 = sigf(cf) * cold + sigf(ci) * tanhf(cg);
    float h2 = sigf(co) * tanhf(c2);
    c[i] = c2;
    h[i] = h2;
    hseq[i] = h2;
}

// ---------------------------------------------------------------------------
extern "C" void kernel_launch(void* const* d_in, const int* in_sizes, int n_in,
                              void* d_out, int out_size, void* d_ws, size_t ws_size,
                              hipStream_t stream)
{
    const float* input  = (const float*)d_in[0];
    const float* fuse_w = (const float*)d_in[1];
    const float* fuse_b = (const float*)d_in[2];
    const float* om_w   = (const float*)d_in[3];
    const float* om_b   = (const float*)d_in[4];
    const float* dcn_w  = (const float*)d_in[5];
    const float* dcn_b  = (const float*)d_in[6];
    const float* conv_w = (const float*)d_in[7];
    const float* conv_b = (const float*)d_in[8];
    const float* cat_w  = (const float*)d_in[9];
    const float* cat_b  = (const float*)d_in[10];
    float* out = (float*)d_out;

    const long CHW = 64L * HW;               // one image of 64 channels
    float* ws = (float*)d_ws;
    float* hseq  = ws;                        // [2][T][B][64][HW] = 20*CHW
    float* hbuf  = hseq + 20L * CHW;          // [B][64][HW]
    float* cbuf  = hbuf + 2L * CHW;           // [B][64][HW]
    float* comb  = cbuf + 2L * CHW;           // [B][64][HW]
    float* om    = comb + 2L * CHW;           // [B][216][HW]
    float* samp  = om + 2L * 216 * HW;        // [B][576][HW]
    float* fused = samp + 2L * 576 * HW;      // [B][128][HW]
    float* cc    = samp;                      // alias: samp dead once fused computed

    dim3 blk(256);
    for (int dir = 0; dir < 2; ++dir) {
        hipMemsetAsync(hbuf, 0, (size_t)(4L * CHW) * sizeof(float), stream);  // h and c
        for (int s = 0; s < TT; ++s) {
            int t = (dir == 0) ? s : (TT - 1 - s);
            // fuse conv: concat(x_t, h) -> comb (64 ch)
            conv3x3_kernel<64, 64, false><<<dim3(36, 4, 2), blk, 0, stream>>>(
                input + (long)t * CHW, (long)TT * CHW, hbuf, CHW,
                fuse_w, fuse_b, comb, CHW, 64);
            // om conv: comb -> om (216 ch)
            conv3x3_kernel<64, 0, false><<<dim3(36, 14, 2), blk, 0, stream>>>(
                comb, CHW, nullptr, 0, om_w, om_b, om, 216L * HW, 216);
            // deformable sampling: h, om -> samp
            dcn_sample_kernel<<<dim3(5184), blk, 0, stream>>>(hbuf, om, samp);
            // einsum (1x1, K=576) + bias + relu -> fused (128 ch)
            conv1x1_relu_kernel<<<dim3(36, 4, 2), blk, 0, stream>>>(samp, dcn_w, dcn_b, fused);
            // big conv: fused -> cc (256 ch)   (cc aliases samp, samp is dead now)
            conv3x3_kernel<128, 0, false><<<dim3(36, 16, 2), blk, 0, stream>>>(
                fused, 128L * HW, nullptr, 0, conv_w, conv_b, cc, 256L * HW, 256);
            // gates -> h, c, hseq[dir][t]
            gates_kernel<<<dim3(4608), blk, 0, stream>>>(
                cc, hbuf, cbuf, hseq + ((long)dir * TT + t) * 2L * CHW);
        }
    }
    // final conv: concat(fwd, bwd) (128 ch) -> out (64 ch), output permuted (t,b)->(b,t)
    conv3x3_kernel<64, 64, true><<<dim3(36, 4, 10), blk, 0, stream>>>(
        hseq, CHW, hseq + 10L * CHW, CHW, cat_w, cat_b, out, CHW, 64);
}